// Round 9
// baseline (2145.064 us; speedup 1.0000x reference)
//
#include <hip/hip_runtime.h>

#define N_NODES 4096
#define H_DIM 32
#define F_INPUT 5
#define ROLLS 200
#define NBLK 256
#define NBUF 64                          // Mt ring: write-once per 64 steps
#define MT_ELEMS ((size_t)H_DIM * N_NODES)   // 131072 shorts = 256 KiB

typedef __attribute__((ext_vector_type(8))) short bf16x8;
typedef __attribute__((ext_vector_type(4))) float fx4;

__device__ __forceinline__ unsigned short f2bf(float f) {
  unsigned int u = __builtin_bit_cast(unsigned int, f);
  u += 0x7fffu + ((u >> 16) & 1u);   // round-to-nearest-even (inputs are benign, no NaN/inf)
  return (unsigned short)(u >> 16);
}

// wave w consumes Mt K-chunk produced by blocks 32w..32w+31: wait on those
// 32 flags (1/lane, lanes 32-63 duplicate). Union over 8 waves = all 256.
__device__ __forceinline__ void wait_group(const unsigned* flags, int wave,
                                           int lane, unsigned target) {
  const unsigned* f = flags + (wave << 5) + (lane & 31);
  for (;;) {
    unsigned v = __hip_atomic_load(f, __ATOMIC_RELAXED,
                                   __HIP_MEMORY_SCOPE_AGENT);
    if (__ballot(v >= target) == ~0ull) break;
    __builtin_amdgcn_s_sleep(1);
  }
  asm volatile("" ::: "memory");
  __builtin_amdgcn_sched_barrier(0);
}

// two-wave (waves 0,1) LDS barrier: monotonic counter, target = 2*(t+1)
__device__ __forceinline__ void pair_bar(unsigned* ctr, int lane,
                                         unsigned want) {
  asm volatile("s_waitcnt lgkmcnt(0)" ::: "memory");   // prior LDS writes done
  if (lane == 0)
    __hip_atomic_fetch_add(ctr, 1u, __ATOMIC_RELAXED,
                           __HIP_MEMORY_SCOPE_WORKGROUP);
  while (__hip_atomic_load(ctr, __ATOMIC_RELAXED,
                           __HIP_MEMORY_SCOPE_WORKGROUP) < want) {}
  asm volatile("" ::: "memory");
  __builtin_amdgcn_sched_barrier(0);
}

// Publish this block's 1 KB Mt slot: each of the 4 store instructions is a
// 256 B fully-contiguous burst (64 lanes x 4 B) -> full-line write-through,
// no partial-line RMW (fixes the 4x WRITE_SIZE amplification of r8).
// Slot layout (shorts): h*16 + row; dword d covers shorts 2d,2d+1.
__device__ __forceinline__ void store_mt_block(unsigned short* mtblk,
                                               const unsigned short* tile,
                                               int lane) {
  unsigned* base = (unsigned*)mtblk;
#pragma unroll
  for (int j = 0; j < 4; ++j) {
    int d = j * 64 + lane;           // dword index 0..255
    int h = d >> 3;                  // H index 0..31
    int rr = 2 * (d & 7);            // row 0,2,..,14
    unsigned lo = tile[rr * 48 + h];
    unsigned hi = tile[(rr + 1) * 48 + h];
    __hip_atomic_store(base + d, lo | (hi << 16), __ATOMIC_RELAXED,
                       __HIP_MEMORY_SCOPE_AGENT);
  }
}

// Persistent cooperative kernel, role-split waves:
//   waves 2-7: {flag-wait, A@M K-chunk MFMAs, red write, barrier} only.
//   waves 0,1: + fused tail in-register (reduce->gates->LSTM->M_next->publish)
//              with 3 two-wave LDS pair-barriers; c-state lives in VGPRs.
// The next-step flag-wait (own flag published by wave 0 after red is read)
// guards red against overwrite — no extra full barrier needed.
__global__ __launch_bounds__(512, 2) void k_roll(
    const float* __restrict__ A, const float* __restrict__ X,
    const float* __restrict__ Wx, const float* __restrict__ Wh, const float* __restrict__ Wc,
    const float* __restrict__ Wih, const float* __restrict__ Whh,
    const float* __restrict__ b_ih, const float* __restrict__ b_hh,
    const float* __restrict__ Wfc, const float* __restrict__ b_fc,
    float* __restrict__ out,
    unsigned short* __restrict__ bufs, unsigned* __restrict__ flags) {

  __shared__ __align__(16) float red[8 * 16 * 36];          // pad 36 (16B-aligned rows)
  __shared__ __align__(16) unsigned short hnB[16 * 48];     // h bf16, A-frag layout
  __shared__ __align__(16) unsigned short cnB[16 * 48];     // c_new bf16 (M_next A-op)
  __shared__ __align__(16) unsigned short MnB[16 * 48];
  __shared__ __align__(16) float xLds[16 * 8];
  __shared__ __align__(16) float hFin[16 * 32];             // fp32 h_final for FC
  __shared__ unsigned pb[3];                                // pair-barrier counters

  const int tid  = threadIdx.x;
  const int wave = tid >> 6;        // 0..7
  const int lane = tid & 63;
  const int l15  = lane & 15;
  const int quad = lane >> 4;       // 0..3
  const int bid  = blockIdx.x;
  const int row0 = bid << 4;

  // ---- prologue: A fragments fp32->bf16 into VGPRs (once) ----
  bf16x8 areg[16];
  {
    const float* Ap = A + (size_t)(row0 + l15) * N_NODES + wave * 512 + quad * 8;
#pragma unroll
    for (int kk = 0; kk < 16; ++kk) {
      bf16x8 a;
#pragma unroll
      for (int j = 0; j < 8; ++j) a[j] = (short)f2bf(Ap[kk * 32 + j]);
      areg[kk] = a;
    }
  }

  // waves 0,1 own ALL gate tiles for their k-half: wave w, gate q, col
  // n_q = q*32 + w*16 + l15. B-frags + biases + M_next weights.
  const int kcol = (wave << 4) + l15;     // 0..31 for waves 0,1
  bf16x8 bIq[4], bHq[4], bWh, bWc;
  float biasq[4], wx5[F_INPUT];
  if (wave < 2) {
#pragma unroll
    for (int q = 0; q < 4; ++q) {
      int n = q * 32 + kcol;
#pragma unroll
      for (int j = 0; j < 8; ++j) {
        bIq[q][j] = (short)f2bf(Wih[n * 32 + quad * 8 + j]);
        bHq[q][j] = (short)f2bf(Whh[n * 32 + quad * 8 + j]);
      }
      biasq[q] = b_ih[n] + b_hh[n];
    }
#pragma unroll
    for (int j = 0; j < 8; ++j) {
      bWh[j] = (short)f2bf(Wh[(quad * 8 + j) * H_DIM + kcol]);
      bWc[j] = (short)f2bf(Wc[(quad * 8 + j) * H_DIM + kcol]);
    }
#pragma unroll
    for (int f = 0; f < F_INPUT; ++f) wx5[f] = Wx[f * H_DIM + kcol];
  }
  fx4 c4 = {0.f, 0.f, 0.f, 0.f};          // c state in registers (waves 0,1)

  // init: hnB = 0 (h0 = 0), pair counters, Mt0 = (x0 @ Wx)^T
  for (int i = tid; i < 16 * 48; i += 512) hnB[i] = 0;
  if (tid == 0) { pb[0] = 0; pb[1] = 0; pb[2] = 0; }
  {
    int r = tid >> 5, k = tid & 31;
    float s = 0.f;
#pragma unroll
    for (int f = 0; f < F_INPUT; ++f)
      s += X[(size_t)(row0 + r) * F_INPUT + f] * Wx[f * H_DIM + k];
    MnB[r * 48 + k] = f2bf(s);
  }
  __syncthreads();
  if (wave == 0) {
    store_mt_block(bufs + (size_t)bid * 512, MnB, lane);
    asm volatile("s_waitcnt vmcnt(0)" ::: "memory");
    if (lane == 0)
      __hip_atomic_store(&flags[bid], 1u, __ATOMIC_RELAXED,
                         __HIP_MEMORY_SCOPE_AGENT);
  }

  for (int t = 0; t < ROLLS; ++t) {
    const unsigned short* m0 = bufs + (size_t)(t & (NBUF - 1)) * MT_ELEMS;
    unsigned short* m1 = bufs + (size_t)((t + 1) & (NBUF - 1)) * MT_ELEMS;

    // ring wrap (t=0,64,128,192): one L1/L2 tag-invalidate before reuse
    if ((t & (NBUF - 1)) == 0) {
      __syncthreads();
      if (tid < 64)
        __builtin_amdgcn_fence(__ATOMIC_ACQUIRE, "agent");
      __syncthreads();
    }

    wait_group(flags, wave, lane, (unsigned)(t + 1));

    // stage x_{t+1} (waves 0,1; consumed by same waves in this step's tail)
    if (t + 1 < ROLLS && tid < 128) {
      int r = tid >> 3, f = tid & 7;
      if (f < F_INPUT)
        xLds[r * 8 + f] = X[(size_t)(t + 1) * N_NODES * F_INPUT +
                            (size_t)(row0 + r) * F_INPUT + f];
    }

    // ---- phase A (all waves): A@M split-K; block-major Mt addressing ----
    fx4 acc0 = {0.f, 0.f, 0.f, 0.f}, acc1 = {0.f, 0.f, 0.f, 0.f};
    {
      const unsigned short* Bb = m0 + ((wave << 5) + (quad >> 1)) * 512
                                    + l15 * 16 + (quad & 1) * 8;
      bf16x8 b0s[16], b1s[16];
#pragma unroll
      for (int s = 0; s < 16; ++s) {
        b0s[s] = *(const bf16x8*)(Bb + s * 1024);
        b1s[s] = *(const bf16x8*)(Bb + s * 1024 + 256);
      }
      __builtin_amdgcn_sched_barrier(0);
#pragma unroll
      for (int s = 0; s < 16; ++s) {
        acc0 = __builtin_amdgcn_mfma_f32_16x16x32_bf16(areg[s], b0s[s], acc0, 0, 0, 0);
        acc1 = __builtin_amdgcn_mfma_f32_16x16x32_bf16(areg[s], b1s[s], acc1, 0, 0, 0);
      }
    }
#pragma unroll
    for (int r = 0; r < 4; ++r) {
      red[(wave * 16 + quad * 4 + r) * 36 + l15]      = acc0[r];
      red[(wave * 16 + quad * 4 + r) * 36 + 16 + l15] = acc1[r];
    }
    __syncthreads();    // red complete — waves 2-7 loop back to next wait

    if (wave < 2) {
      const unsigned want = 2u * (unsigned)(t + 1);
      // fused reduce: aI fragment in-register (identical order/rounding in
      // both waves -> bit-identical inp)
      bf16x8 aI;
#pragma unroll
      for (int j = 0; j < 8; ++j) {
        int n = quad * 8 + j;
        float s = 0.f;
#pragma unroll
        for (int w = 0; w < 8; ++w) s += red[(w * 16 + l15) * 36 + n];
        aI[j] = (short)f2bf(s);
      }
      bf16x8 aH = *(const bf16x8*)(hnB + l15 * 48 + quad * 8);
      pair_bar(&pb[0], lane, want);      // both waves consumed hnB (aH)

      // gates: 4 tiles (i,f,g,o) x (inp,h) MFMAs
      fx4 gq0 = {0,0,0,0}, gq1 = {0,0,0,0}, gq2 = {0,0,0,0}, gq3 = {0,0,0,0};
      gq0 = __builtin_amdgcn_mfma_f32_16x16x32_bf16(aI, bIq[0], gq0, 0, 0, 0);
      gq0 = __builtin_amdgcn_mfma_f32_16x16x32_bf16(aH, bHq[0], gq0, 0, 0, 0);
      gq1 = __builtin_amdgcn_mfma_f32_16x16x32_bf16(aI, bIq[1], gq1, 0, 0, 0);
      gq1 = __builtin_amdgcn_mfma_f32_16x16x32_bf16(aH, bHq[1], gq1, 0, 0, 0);
      gq2 = __builtin_amdgcn_mfma_f32_16x16x32_bf16(aI, bIq[2], gq2, 0, 0, 0);
      gq2 = __builtin_amdgcn_mfma_f32_16x16x32_bf16(aH, bHq[2], gq2, 0, 0, 0);
      gq3 = __builtin_amdgcn_mfma_f32_16x16x32_bf16(aI, bIq[3], gq3, 0, 0, 0);
      gq3 = __builtin_amdgcn_mfma_f32_16x16x32_bf16(aH, bHq[3], gq3, 0, 0, 0);

      // LSTM in-register: lane owns rows quad*4+r at column kcol
#pragma unroll
      for (int r = 0; r < 4; ++r) {
        int m = quad * 4 + r;
        float gi = gq0[r] + biasq[0];
        float gf = gq1[r] + biasq[1];
        float gg = gq2[r] + biasq[2];
        float go = gq3[r] + biasq[3];
        float i_ = 1.f / (1.f + __expf(-gi));
        float f_ = 1.f / (1.f + __expf(-gf));
        float g_ = tanhf(gg);
        float o_ = 1.f / (1.f + __expf(-go));
        float cn = f_ * c4[r] + i_ * g_;
        float hn = o_ * tanhf(cn);
        c4[r] = cn;
        hnB[m * 48 + kcol] = f2bf(hn);
        cnB[m * 48 + kcol] = f2bf(cn);
        if (t == ROLLS - 1) hFin[m * 32 + kcol] = hn;
      }
      pair_bar(&pb[1], lane, want);      // hnB/cnB complete

      if (t < ROLLS - 1) {
        // M_next = h@Wh + c@Wc + x@Wx  (cols kcol per wave)
        bf16x8 aHn = *(const bf16x8*)(hnB + l15 * 48 + quad * 8);
        bf16x8 aCn = *(const bf16x8*)(cnB + l15 * 48 + quad * 8);
        fx4 m4 = {0.f, 0.f, 0.f, 0.f};
        m4 = __builtin_amdgcn_mfma_f32_16x16x32_bf16(aHn, bWh, m4, 0, 0, 0);
        m4 = __builtin_amdgcn_mfma_f32_16x16x32_bf16(aCn, bWc, m4, 0, 0, 0);
#pragma unroll
        for (int r = 0; r < 4; ++r) {
          int m = quad * 4 + r;
          float xs = m4[r];
#pragma unroll
          for (int f = 0; f < F_INPUT; ++f) xs += xLds[m * 8 + f] * wx5[f];
          MnB[m * 48 + kcol] = f2bf(xs);
        }
        pair_bar(&pb[2], lane, want);    // MnB complete
        if (wave == 0) {
          store_mt_block(m1 + (size_t)bid * 512, MnB, lane);
          asm volatile("s_waitcnt vmcnt(0)" ::: "memory");
          if (lane == 0)
            __hip_atomic_store(&flags[bid], (unsigned)(t + 2), __ATOMIC_RELAXED,
                               __HIP_MEMORY_SCOPE_AGENT);
        }
      }
    }
  }

  // ---- epilogue (wave 0): out = h_final @ Wfc^T + b_fc (fp32 h) ----
  if (wave == 0 && lane < 16) {
    float s = b_fc[0];
#pragma unroll
    for (int k = 0; k < 32; ++k) s += hFin[lane * 32 + k] * Wfc[k];
    out[row0 + lane] = s;
  }
}

extern "C" void kernel_launch(void* const* d_in, const int* in_sizes, int n_in,
                              void* d_out, int out_size, void* d_ws, size_t ws_size,
                              hipStream_t stream) {
  (void)in_sizes; (void)n_in; (void)out_size; (void)ws_size;
  const float* X   = (const float*)d_in[0];
  const float* A   = (const float*)d_in[1];
  const float* Wx  = (const float*)d_in[2];
  const float* Wh  = (const float*)d_in[3];
  const float* Wc  = (const float*)d_in[4];
  const float* Wih = (const float*)d_in[5];
  const float* Whh = (const float*)d_in[6];
  const float* bih = (const float*)d_in[7];
  const float* bhh = (const float*)d_in[8];
  const float* Wfc = (const float*)d_in[9];
  const float* bfc = (const float*)d_in[10];
  float* outp = (float*)d_out;

  char* ws = (char*)d_ws;
  unsigned short* bufs = (unsigned short*)ws;
  ws += (size_t)NBUF * MT_ELEMS * 2;           // 16 MiB Mt ring
  unsigned* flags = (unsigned*)ws;
  ws += NBLK * sizeof(unsigned);

  // epoch flags must start at 0 every call (graph-capturable async memset)
  (void)hipMemsetAsync(flags, 0, NBLK * sizeof(unsigned), stream);

  void* args[] = {
    (void*)&A, (void*)&X, (void*)&Wx, (void*)&Wh, (void*)&Wc,
    (void*)&Wih, (void*)&Whh, (void*)&bih, (void*)&bhh,
    (void*)&Wfc, (void*)&bfc, (void*)&outp,
    (void*)&bufs, (void*)&flags
  };
  (void)hipLaunchCooperativeKernel((const void*)k_roll, dim3(NBLK), dim3(512),
                                   args, 0, stream);
}

// Round 11
// 1779.644 us; speedup vs baseline: 1.2053x; 1.2053x over previous
//
#include <hip/hip_runtime.h>

#define N_NODES 4096
#define H_DIM 32
#define F_INPUT 5
#define ROLLS 200
#define NBLK 256
#define NBUF 64                          // Mt ring: write-once per 64 steps
#define MT_ELEMS ((size_t)H_DIM * N_NODES)   // 131072 shorts = 256 KiB

typedef __attribute__((ext_vector_type(8))) short bf16x8;
typedef __attribute__((ext_vector_type(4))) float fx4;

__device__ __forceinline__ unsigned short f2bf(float f) {
  unsigned int u = __builtin_bit_cast(unsigned int, f);
  u += 0x7fffu + ((u >> 16) & 1u);   // round-to-nearest-even (inputs are benign, no NaN/inf)
  return (unsigned short)(u >> 16);
}

// Single-poller barrier: wave 0 polls all 256 block flags (4/lane,
// agent-scope = L2-bypassing loads); waves 1-7 park at the syncthreads.
__device__ __forceinline__ void wait_all(const unsigned* flags, int tid,
                                         unsigned target) {
  if (tid < 64) {
    for (;;) {
      bool ok = true;
#pragma unroll
      for (int j = 0; j < 4; ++j) {
        unsigned v = __hip_atomic_load(&flags[tid * 4 + j], __ATOMIC_RELAXED,
                                       __HIP_MEMORY_SCOPE_AGENT);
        ok = ok && (v >= target);
      }
      if (__ballot(ok) == ~0ull) break;
      __builtin_amdgcn_s_sleep(1);
    }
  }
  __syncthreads();
  asm volatile("" ::: "memory");   // keep Mt loads below the wait
}

// Publish this block's 1 KB Mt slot: each of the 4 store instructions is a
// 256 B fully-contiguous burst (64 lanes x 4 B) -> full-line write-through,
// no partial-line RMW (r9-confirmed: WRITE_SIZE 208->80 MB).
// Slot layout (shorts): h*16 + row — identical bytes to the r8 layout.
__device__ __forceinline__ void store_mt_block(unsigned short* mtblk,
                                               const unsigned short* tile,
                                               int lane) {
  unsigned* base = (unsigned*)mtblk;
#pragma unroll
  for (int j = 0; j < 4; ++j) {
    int d = j * 64 + lane;           // dword index 0..255
    int h = d >> 3;                  // H index 0..31
    int rr = 2 * (d & 7);            // row 0,2,..,14
    unsigned lo = tile[rr * 48 + h];
    unsigned hi = tile[(rr + 1) * 48 + h];
    __hip_atomic_store(base + d, lo | (hi << 16), __ATOMIC_RELAXED,
                       __HIP_MEMORY_SCOPE_AGENT);
  }
}

// Persistent cooperative kernel (round-8 structure + contiguous publish).
// grid = 256 blocks (1/CU), 512 threads (8 waves), 16 rows/block. A in
// VGPRs; h/c in LDS; Mt ring (64) in global, block-major layout:
// buffer + pb*512 + h*16 + node_within_pb.
__global__ __launch_bounds__(512, 2) void k_roll(
    const float* __restrict__ A, const float* __restrict__ X,
    const float* __restrict__ Wx, const float* __restrict__ Wh, const float* __restrict__ Wc,
    const float* __restrict__ Wih, const float* __restrict__ Whh,
    const float* __restrict__ b_ih, const float* __restrict__ b_hh,
    const float* __restrict__ Wfc, const float* __restrict__ b_fc,
    float* __restrict__ out,
    unsigned short* __restrict__ bufs, unsigned* __restrict__ flags) {

  __shared__ __align__(16) float red[8 * 16 * 33];          // split-K partials (pad 33)
  __shared__ __align__(16) unsigned short inpB[16 * 48];    // inp bf16, A-frag layout
  __shared__ __align__(16) unsigned short hB[16 * 48];      // persistent h (bf16 frag)
  __shared__ __align__(16) unsigned short cnB[16 * 48];     // c_new bf16 (for M_next)
  __shared__ __align__(16) unsigned short MnB[16 * 48];
  __shared__ __align__(16) float cB[16 * 32];               // persistent c (fp32)
  __shared__ __align__(16) float gatesLds[16 * 132];
  __shared__ __align__(16) float xLds[16 * 8];

  const int tid  = threadIdx.x;
  const int wave = tid >> 6;        // 0..7
  const int lane = tid & 63;
  const int l15  = lane & 15;
  const int quad = lane >> 4;       // 0..3
  const int bid  = blockIdx.x;
  const int row0 = bid << 4;

  // ---- prologue: A fragments fp32->bf16 into VGPRs (once) ----
  bf16x8 areg[16];
  {
    const float* Ap = A + (size_t)(row0 + l15) * N_NODES + wave * 512 + quad * 8;
#pragma unroll
    for (int kk = 0; kk < 16; ++kk) {
      bf16x8 a;
#pragma unroll
      for (int j = 0; j < 8; ++j) a[j] = (short)f2bf(Ap[kk * 32 + j]);
      areg[kk] = a;
    }
  }

  // gate weight fragments: wave w owns gate cols [16w, 16w+16)
  const int g = (wave << 4) + l15;
  bf16x8 bI, bH;
#pragma unroll
  for (int j = 0; j < 8; ++j) {
    bI[j] = (short)f2bf(Wih[g * 32 + quad * 8 + j]);
    bH[j] = (short)f2bf(Whh[g * 32 + quad * 8 + j]);
  }
  const float bias = b_ih[g] + b_hh[g];

  // M_next weight fragments (waves 0,1 only): WhT[n][k]=Wh[k][n]
  bf16x8 bWh, bWc;
  float wx5[F_INPUT];
  if (wave < 2) {
#pragma unroll
    for (int j = 0; j < 8; ++j) {
      bWh[j] = (short)f2bf(Wh[(quad * 8 + j) * H_DIM + g]);
      bWc[j] = (short)f2bf(Wc[(quad * 8 + j) * H_DIM + g]);
    }
#pragma unroll
    for (int f = 0; f < F_INPUT; ++f) wx5[f] = Wx[f * H_DIM + g];
  }

  // h = c = 0 ; Mt0 = (x0 @ Wx)^T staged in LDS
  {
    int r = tid >> 5, k = tid & 31;
    hB[r * 48 + k] = 0;       // f2bf(0)==0
    cB[r * 32 + k] = 0.f;
    float s = 0.f;
#pragma unroll
    for (int f = 0; f < F_INPUT; ++f)
      s += X[(size_t)(row0 + r) * F_INPUT + f] * Wx[f * H_DIM + k];
    MnB[r * 48 + k] = f2bf(s);
  }
  __syncthreads();
  if (wave == 0) {             // store Mt0 (1 KB contiguous) + publish epoch 1
    store_mt_block(bufs + (size_t)bid * 512, MnB, lane);
    asm volatile("s_waitcnt vmcnt(0)" ::: "memory");
    if (lane == 0)
      __hip_atomic_store(&flags[bid], 1u, __ATOMIC_RELAXED,
                         __HIP_MEMORY_SCOPE_AGENT);
  }

  for (int t = 0; t < ROLLS; ++t) {
    const unsigned short* m0 = bufs + (size_t)(t & (NBUF - 1)) * MT_ELEMS;
    unsigned short* m1 = bufs + (size_t)((t + 1) & (NBUF - 1)) * MT_ELEMS;

    // window wrap (t = 0,64,128,192): invalidate L1/L2 once so reused ring
    // buffers can't serve stale lines; also clears prior-call lines at t=0
    if ((t & (NBUF - 1)) == 0) {
      __syncthreads();
      if (tid < 64)
        __builtin_amdgcn_fence(__ATOMIC_ACQUIRE, "agent");
      __syncthreads();
    }

    // wave 0 polls all 256 producer flags; everyone else parks at barrier
    wait_all(flags, tid, (unsigned)(t + 1));

    // stage x_{t+1} early: completes under the MFMAs.
    // tid<128 = waves 0,1 — same waves read xLds in phase E (in-wave order)
    if (t + 1 < ROLLS && tid < 128) {
      int r = tid >> 3, f = tid & 7;
      if (f < F_INPUT)
        xLds[r * 8 + f] = X[(size_t)(t + 1) * N_NODES * F_INPUT +
                            (size_t)(row0 + r) * F_INPUT + f];
    }

    // ---- phase A: issue all 32 Mt loads (block-major addressing), then
    // the MFMA chain. Wave w, subtile s: producer block pb = w*32+s*2+
    // (quad>>1); b0 = [pb][h=l15][(quad&1)*8..+7], b1 = [pb][16+l15][...].
    fx4 acc0 = {0.f, 0.f, 0.f, 0.f}, acc1 = {0.f, 0.f, 0.f, 0.f};
    {
      const unsigned short* Bb = m0 + ((wave << 5) + (quad >> 1)) * 512
                                    + l15 * 16 + (quad & 1) * 8;
      bf16x8 b0s[16], b1s[16];
#pragma unroll
      for (int s = 0; s < 16; ++s) {
        b0s[s] = *(const bf16x8*)(Bb + s * 1024);
        b1s[s] = *(const bf16x8*)(Bb + s * 1024 + 256);
      }
      __builtin_amdgcn_sched_barrier(0);   // keep all loads issued first
#pragma unroll
      for (int s = 0; s < 16; ++s) {
        acc0 = __builtin_amdgcn_mfma_f32_16x16x32_bf16(areg[s], b0s[s], acc0, 0, 0, 0);
        acc1 = __builtin_amdgcn_mfma_f32_16x16x32_bf16(areg[s], b1s[s], acc1, 0, 0, 0);
      }
    }
#pragma unroll
    for (int r = 0; r < 4; ++r) {
      red[(wave * 16 + quad * 4 + r) * 33 + l15]      = acc0[r];
      red[(wave * 16 + quad * 4 + r) * 33 + 16 + l15] = acc1[r];
    }
    __syncthreads();

    // ---- phase B: reduce 8 partials -> inp bf16 ----
    {
      int m = tid >> 5, n = tid & 31;
      float s = 0.f;
#pragma unroll
      for (int w = 0; w < 8; ++w) s += red[(w * 16 + m) * 33 + n];
      inpB[m * 48 + n] = f2bf(s);
    }
    __syncthreads();

    // ---- phase C: gates(16x128) = inp@Wih^T + h@Whh^T + b ----
    {
      bf16x8 aI = *(const bf16x8*)(inpB + l15 * 48 + quad * 8);
      bf16x8 aH = *(const bf16x8*)(hB   + l15 * 48 + quad * 8);
      fx4 gacc = {0.f, 0.f, 0.f, 0.f};
      gacc = __builtin_amdgcn_mfma_f32_16x16x32_bf16(aI, bI, gacc, 0, 0, 0);
      gacc = __builtin_amdgcn_mfma_f32_16x16x32_bf16(aH, bH, gacc, 0, 0, 0);
#pragma unroll
      for (int r = 0; r < 4; ++r) gatesLds[(quad * 4 + r) * 132 + g] = gacc[r] + bias;
    }
    __syncthreads();

    // ---- phase D: LSTM cell elementwise (fp32 state in LDS) ----
    {
      int r = tid >> 5, k = tid & 31;
      float gi = gatesLds[r * 132 + k];
      float gf = gatesLds[r * 132 + 32 + k];
      float gg = gatesLds[r * 132 + 64 + k];
      float go = gatesLds[r * 132 + 96 + k];
      float i_ = 1.f / (1.f + __expf(-gi));
      float f_ = 1.f / (1.f + __expf(-gf));
      float g_ = tanhf(gg);
      float o_ = 1.f / (1.f + __expf(-go));
      float cn = f_ * cB[r * 32 + k] + i_ * g_;
      float hn = o_ * tanhf(cn);
      cB[r * 32 + k] = cn;
      hB[r * 48 + k] = f2bf(hn);        // next step's h fragment
      cnB[r * 48 + k] = f2bf(cn);
      if (t == ROLLS - 1) gatesLds[r * 132 + k] = hn * Wfc[k];
    }
    __syncthreads();

    // ---- phase E: M_next = h@Wh + c@Wc + x@Wx (waves 0,1) ----
    if (t < ROLLS - 1) {
      if (wave < 2) {
        bf16x8 aH = *(const bf16x8*)(hB  + l15 * 48 + quad * 8);
        bf16x8 aC = *(const bf16x8*)(cnB + l15 * 48 + quad * 8);
        fx4 m4 = {0.f, 0.f, 0.f, 0.f};
        m4 = __builtin_amdgcn_mfma_f32_16x16x32_bf16(aH, bWh, m4, 0, 0, 0);
        m4 = __builtin_amdgcn_mfma_f32_16x16x32_bf16(aC, bWc, m4, 0, 0, 0);
#pragma unroll
        for (int r = 0; r < 4; ++r) {
          int m = quad * 4 + r;
          float xs = m4[r];
#pragma unroll
          for (int f = 0; f < F_INPUT; ++f) xs += xLds[m * 8 + f] * wx5[f];
          MnB[m * 48 + g] = f2bf(xs);
        }
      }
      __syncthreads();                 // MnB ready — waves 1-7 fall through
      if (wave == 0) {                 // publish: 1 KB contiguous + drain + flag
        store_mt_block(m1 + (size_t)bid * 512, MnB, lane);
        asm volatile("s_waitcnt vmcnt(0)" ::: "memory");
        if (lane == 0)
          __hip_atomic_store(&flags[bid], (unsigned)(t + 2), __ATOMIC_RELAXED,
                             __HIP_MEMORY_SCOPE_AGENT);
      }
    }
  }

  // ---- epilogue: out = h_final @ Wfc^T + b_fc ----
  if (tid < 16) {
    float s = b_fc[0];
#pragma unroll
    for (int k = 0; k < 32; ++k) s += gatesLds[tid * 132 + k];
    out[row0 + tid] = s;
  }
}

extern "C" void kernel_launch(void* const* d_in, const int* in_sizes, int n_in,
                              void* d_out, int out_size, void* d_ws, size_t ws_size,
                              hipStream_t stream) {
  (void)in_sizes; (void)n_in; (void)out_size; (void)ws_size;
  const float* X   = (const float*)d_in[0];
  const float* A   = (const float*)d_in[1];
  const float* Wx  = (const float*)d_in[2];
  const float* Wh  = (const float*)d_in[3];
  const float* Wc  = (const float*)d_in[4];
  const float* Wih = (const float*)d_in[5];
  const float* Whh = (const float*)d_in[6];
  const float* bih = (const float*)d_in[7];
  const float* bhh = (const float*)d_in[8];
  const float* Wfc = (const float*)d_in[9];
  const float* bfc = (const float*)d_in[10];
  float* outp = (float*)d_out;

  char* ws = (char*)d_ws;
  unsigned short* bufs = (unsigned short*)ws;
  ws += (size_t)NBUF * MT_ELEMS * 2;           // 16 MiB Mt ring
  unsigned* flags = (unsigned*)ws;
  ws += NBLK * sizeof(unsigned);

  // epoch flags must start at 0 every call (graph-capturable async memset)
  (void)hipMemsetAsync(flags, 0, NBLK * sizeof(unsigned), stream);

  void* args[] = {
    (void*)&A, (void*)&X, (void*)&Wx, (void*)&Wh, (void*)&Wc,
    (void*)&Wih, (void*)&Whh, (void*)&bih, (void*)&bhh,
    (void*)&Wfc, (void*)&bfc, (void*)&outp,
    (void*)&bufs, (void*)&flags
  };
  (void)hipLaunchCooperativeKernel((const void*)k_roll, dim3(NBLK), dim3(512),
                                   args, 0, stream);
}